// Round 1
// baseline (53147.791 us; speedup 1.0000x reference)
//
#include <hip/hip_runtime.h>
#include <cstdint>
#include <cstddef>

#define Bsz 64
#define Ssz 2048
#define Isz 256
#define Hsz 512

// ============================================================================
// Kernel 1: xproj GEMM
//   out[m][n] = sum_k x[m][k] * Wih[n][k] + bih[n] + bhh[n]
//   M = Bsz*Ssz = 131072, N = Hsz = 512, K = Isz = 256
//   Tile 128x128, K-tile 64, 256 threads, 8x8 microtile, fp32.
//   Writes xproj straight into d_out; the scan kernel overwrites it in place.
// ============================================================================
__global__ __launch_bounds__(256) void xproj_gemm(
    const float* __restrict__ x, const float* __restrict__ Wih,
    const float* __restrict__ bih, const float* __restrict__ bhh,
    float* __restrict__ out)
{
    // k-major LDS tiles (transposed on store) so the inner loop reads
    // contiguous float4 along m / n. Stride 136 keeps float4 alignment
    // (136*4B = 544B, multiple of 16) and breaks power-of-2 bank strides.
    __shared__ float As[64][136];
    __shared__ float Bs[64][136];

    const int tid = threadIdx.x;
    const int tx = tid & 15;        // 0..15 -> n microtile
    const int ty = tid >> 4;        // 0..15 -> m microtile
    const int m_blk = blockIdx.y * 128;
    const int n_blk = blockIdx.x * 128;

    float acc[8][8];
#pragma unroll
    for (int i = 0; i < 8; ++i)
#pragma unroll
        for (int j = 0; j < 8; ++j) acc[i][j] = 0.f;

    // staging assignment: each thread loads 32 contiguous k for one row
    const int srow = tid >> 1;          // 0..127
    const int skh  = (tid & 1) * 32;    // 0 or 32

    for (int kt = 0; kt < Isz; kt += 64) {
        const float* ga = x   + (size_t)(m_blk + srow) * Isz + kt + skh;
        const float* gb = Wih + (size_t)(n_blk + srow) * Isz + kt + skh;
#pragma unroll
        for (int q = 0; q < 8; ++q) {
            const float4 va = *(const float4*)(ga + q * 4);
            As[skh + q * 4 + 0][srow] = va.x;
            As[skh + q * 4 + 1][srow] = va.y;
            As[skh + q * 4 + 2][srow] = va.z;
            As[skh + q * 4 + 3][srow] = va.w;
            const float4 vb = *(const float4*)(gb + q * 4);
            Bs[skh + q * 4 + 0][srow] = vb.x;
            Bs[skh + q * 4 + 1][srow] = vb.y;
            Bs[skh + q * 4 + 2][srow] = vb.z;
            Bs[skh + q * 4 + 3][srow] = vb.w;
        }
        __syncthreads();

#pragma unroll 4
        for (int k = 0; k < 64; ++k) {
            const float4 a0 = *(const float4*)&As[k][ty * 8];
            const float4 a1 = *(const float4*)&As[k][ty * 8 + 4];
            const float4 b0 = *(const float4*)&Bs[k][tx * 8];
            const float4 b1 = *(const float4*)&Bs[k][tx * 8 + 4];
            const float av[8] = {a0.x, a0.y, a0.z, a0.w, a1.x, a1.y, a1.z, a1.w};
            const float bv[8] = {b0.x, b0.y, b0.z, b0.w, b1.x, b1.y, b1.z, b1.w};
#pragma unroll
            for (int i = 0; i < 8; ++i)
#pragma unroll
                for (int j = 0; j < 8; ++j)
                    acc[i][j] = fmaf(av[i], bv[j], acc[i][j]);
        }
        __syncthreads();
    }

    const int m0 = m_blk + ty * 8;
    const int n0 = n_blk + tx * 8;
    float bias[8];
#pragma unroll
    for (int j = 0; j < 8; ++j) bias[j] = bih[n0 + j] + bhh[n0 + j];
#pragma unroll
    for (int i = 0; i < 8; ++i) {
        const float4 o0 = make_float4(acc[i][0] + bias[0], acc[i][1] + bias[1],
                                      acc[i][2] + bias[2], acc[i][3] + bias[3]);
        const float4 o1 = make_float4(acc[i][4] + bias[4], acc[i][5] + bias[5],
                                      acc[i][6] + bias[6], acc[i][7] + bias[7]);
        *(float4*)(out + (size_t)(m0 + i) * Hsz + n0)     = o0;
        *(float4*)(out + (size_t)(m0 + i) * Hsz + n0 + 4) = o1;
    }
}

// ============================================================================
// Kernel 2: recurrent scan, one workgroup per batch element.
//   h_t = tanh(xproj[b][t] + W_hh @ h_{t-1}), xproj read from (and h_t
//   written back to) d_out in place.
//   1024 threads = 16 waves. Wave w: rowhalf = w&1, kchunk = w>>1.
//   Thread (w,l): rows j = rowhalf*256 + 4l .. +3, k in [kchunk*64, +64).
//   W_hh tile (4x64 = 256 fp32) lives in VGPRs for the whole kernel.
//   h broadcast via v_readlane -> SGPR operand of v_fmac (no LDS in the
//   inner loop).
// ============================================================================
__device__ __forceinline__ float bcast_lane(float v, int lane) {
    return __builtin_bit_cast(float,
        __builtin_amdgcn_readlane(__builtin_bit_cast(int, v), lane));
}

__global__ __launch_bounds__(1024) void rnn_scan(
    const float* __restrict__ Whh, float* __restrict__ out)
{
    __shared__ float h_lds[Hsz];          // current hidden state (fp32)
    __shared__ float partial[8][Hsz];     // per-kchunk partial sums

    const int b   = blockIdx.x;
    const int tid = threadIdx.x;
    const int w   = tid >> 6;
    const int l   = tid & 63;
    const int rowhalf = w & 1;
    const int kchunk  = w >> 1;
    const int jbase   = rowhalf * 256 + l * 4;   // first of 4 owned rows
    const int kb      = kchunk * 64;             // k-chunk base

    // ---- load the persistent weight tile into registers (one time) ----
    float wreg[4][64];
#pragma unroll
    for (int r = 0; r < 4; ++r) {
        const float* wp = Whh + (size_t)(jbase + r) * Hsz + kb;
#pragma unroll
        for (int q = 0; q < 16; ++q) {
            const float4 v = *(const float4*)(wp + q * 4);
            wreg[r][q * 4 + 0] = v.x;
            wreg[r][q * 4 + 1] = v.y;
            wreg[r][q * 4 + 2] = v.z;
            wreg[r][q * 4 + 3] = v.w;
        }
    }

    if (tid < 128) {
        *(float4*)&h_lds[tid * 4] = make_float4(0.f, 0.f, 0.f, 0.f);
    }
    __syncthreads();

    float* outb = out + (size_t)b * Ssz * Hsz;

    for (int t = 0; t < Ssz; ++t) {
        // issue xproj load early so HBM latency hides under the MACs
        float4 xp = make_float4(0.f, 0.f, 0.f, 0.f);
        if (tid < 128)
            xp = *(const float4*)(outb + (size_t)t * Hsz + tid * 4);

        // each lane grabs one h value of this wave's k-chunk; readlane
        // broadcasts it to the whole wave as an SGPR
        const float hv = h_lds[kb + l];

        float acc0 = 0.f, acc1 = 0.f, acc2 = 0.f, acc3 = 0.f;
#pragma unroll
        for (int kk = 0; kk < 64; ++kk) {
            const float s = bcast_lane(hv, kk);
            acc0 = fmaf(wreg[0][kk], s, acc0);
            acc1 = fmaf(wreg[1][kk], s, acc1);
            acc2 = fmaf(wreg[2][kk], s, acc2);
            acc3 = fmaf(wreg[3][kk], s, acc3);
        }

        *(float4*)&partial[kchunk][jbase] = make_float4(acc0, acc1, acc2, acc3);
        __syncthreads();

        if (tid < 128) {
            float sx = xp.x, sy = xp.y, sz = xp.z, sw = xp.w;
#pragma unroll
            for (int c = 0; c < 8; ++c) {
                const float4 p = *(const float4*)&partial[c][tid * 4];
                sx += p.x; sy += p.y; sz += p.z; sw += p.w;
            }
            const float4 hn = make_float4(tanhf(sx), tanhf(sy),
                                          tanhf(sz), tanhf(sw));
            *(float4*)&h_lds[tid * 4] = hn;                       // publish h_t
            *(float4*)(outb + (size_t)t * Hsz + tid * 4) = hn;    // emit output
        }
        __syncthreads();
    }
}

// ============================================================================
extern "C" void kernel_launch(void* const* d_in, const int* in_sizes, int n_in,
                              void* d_out, int out_size, void* d_ws, size_t ws_size,
                              hipStream_t stream)
{
    const float* x   = (const float*)d_in[0];   // (B,S,I)
    const float* Wih = (const float*)d_in[1];   // (H,I)
    const float* Whh = (const float*)d_in[2];   // (H,H)
    const float* bih = (const float*)d_in[3];   // (H)
    const float* bhh = (const float*)d_in[4];   // (H)
    float* out = (float*)d_out;                 // (B,S,H)

    // xproj -> d_out
    dim3 g1(Hsz / 128, (Bsz * Ssz) / 128);      // (4, 1024)
    xproj_gemm<<<g1, 256, 0, stream>>>(x, Wih, bih, bhh, out);

    // sequential scan, one block per batch element, in-place on d_out
    rnn_scan<<<Bsz, 1024, 0, stream>>>(Whh, out);
}

// Round 2
// 36516.489 us; speedup vs baseline: 1.4554x; 1.4554x over previous
//
#include <hip/hip_runtime.h>
#include <cstdint>
#include <cstddef>

#define Bsz 64
#define Ssz 2048
#define Isz 256
#define Hsz 512

// ============================================================================
// Kernel 1: xproj GEMM  (unchanged from round 1 — ~0.3 ms, near VALU roofline)
//   out[m][n] = sum_k x[m][k] * Wih[n][k] + bih[n] + bhh[n]
// ============================================================================
__global__ __launch_bounds__(256) void xproj_gemm(
    const float* __restrict__ x, const float* __restrict__ Wih,
    const float* __restrict__ bih, const float* __restrict__ bhh,
    float* __restrict__ out)
{
    __shared__ float As[64][136];
    __shared__ float Bs[64][136];

    const int tid = threadIdx.x;
    const int tx = tid & 15;
    const int ty = tid >> 4;
    const int m_blk = blockIdx.y * 128;
    const int n_blk = blockIdx.x * 128;

    float acc[8][8];
#pragma unroll
    for (int i = 0; i < 8; ++i)
#pragma unroll
        for (int j = 0; j < 8; ++j) acc[i][j] = 0.f;

    const int srow = tid >> 1;
    const int skh  = (tid & 1) * 32;

    for (int kt = 0; kt < Isz; kt += 64) {
        const float* ga = x   + (size_t)(m_blk + srow) * Isz + kt + skh;
        const float* gb = Wih + (size_t)(n_blk + srow) * Isz + kt + skh;
#pragma unroll
        for (int q = 0; q < 8; ++q) {
            const float4 va = *(const float4*)(ga + q * 4);
            As[skh + q * 4 + 0][srow] = va.x;
            As[skh + q * 4 + 1][srow] = va.y;
            As[skh + q * 4 + 2][srow] = va.z;
            As[skh + q * 4 + 3][srow] = va.w;
            const float4 vb = *(const float4*)(gb + q * 4);
            Bs[skh + q * 4 + 0][srow] = vb.x;
            Bs[skh + q * 4 + 1][srow] = vb.y;
            Bs[skh + q * 4 + 2][srow] = vb.z;
            Bs[skh + q * 4 + 3][srow] = vb.w;
        }
        __syncthreads();

#pragma unroll 4
        for (int k = 0; k < 64; ++k) {
            const float4 a0 = *(const float4*)&As[k][ty * 8];
            const float4 a1 = *(const float4*)&As[k][ty * 8 + 4];
            const float4 b0 = *(const float4*)&Bs[k][tx * 8];
            const float4 b1 = *(const float4*)&Bs[k][tx * 8 + 4];
            const float av[8] = {a0.x, a0.y, a0.z, a0.w, a1.x, a1.y, a1.z, a1.w};
            const float bv[8] = {b0.x, b0.y, b0.z, b0.w, b1.x, b1.y, b1.z, b1.w};
#pragma unroll
            for (int i = 0; i < 8; ++i)
#pragma unroll
                for (int j = 0; j < 8; ++j)
                    acc[i][j] = fmaf(av[i], bv[j], acc[i][j]);
        }
        __syncthreads();
    }

    const int m0 = m_blk + ty * 8;
    const int n0 = n_blk + tx * 8;
    float bias[8];
#pragma unroll
    for (int j = 0; j < 8; ++j) bias[j] = bih[n0 + j] + bhh[n0 + j];
#pragma unroll
    for (int i = 0; i < 8; ++i) {
        const float4 o0 = make_float4(acc[i][0] + bias[0], acc[i][1] + bias[1],
                                      acc[i][2] + bias[2], acc[i][3] + bias[3]);
        const float4 o1 = make_float4(acc[i][4] + bias[4], acc[i][5] + bias[5],
                                      acc[i][6] + bias[6], acc[i][7] + bias[7]);
        *(float4*)(out + (size_t)(m0 + i) * Hsz + n0)     = o0;
        *(float4*)(out + (size_t)(m0 + i) * Hsz + n0 + 4) = o1;
    }
}

// ============================================================================
// Kernel 2: recurrent scan — one 512-thread block (8 waves, 2 waves/SIMD,
// VGPR cap 256) per batch element.
//   Wave w -> k-chunk [64w, 64w+64). Lane l -> rows {64*i + l}, i=0..7.
//   Rows i=0,1: register-resident (128 VGPR, static indexing only).
//   Rows i=2..7: streamed from L2 every step (shared lines across all blocks
//   on an XCD -> L2-resident), ring-3 float4 buffer, prefetch distance 2,
//   loop-invariant addresses (base VGPR pair + imm offset per sub-chunk).
//   h broadcast: v_readlane -> SGPR operand of v_fmac.
// ============================================================================
__device__ __forceinline__ float bcast_lane(float v, int lane) {
    return __builtin_bit_cast(float,
        __builtin_amdgcn_readlane(__builtin_bit_cast(int, v), lane));
}

__global__ __launch_bounds__(512, 2) void rnn_scan(
    const float* __restrict__ Whh, float* __restrict__ out)
{
    __shared__ float pt[8][Hsz];     // per-k-chunk partials (16 KB)
    __shared__ float h_lds[Hsz];     // current hidden state (2 KB)

    const int b   = blockIdx.x;
    const int tid = threadIdx.x;
    const int w   = tid >> 6;        // wave id 0..7 -> k-chunk
    const int l   = tid & 63;
    const int kb  = w * 64;

    // ---- register-resident weight rows i=0,1 (one-time load) ----
    float wreg[2][64];
#pragma unroll
    for (int i = 0; i < 2; ++i) {
        const float* wp = Whh + (size_t)(i * 64 + l) * Hsz + kb;
#pragma unroll
        for (int q = 0; q < 16; ++q) {
            const float4 v = *(const float4*)(wp + 4 * q);
            wreg[i][4 * q + 0] = v.x;
            wreg[i][4 * q + 1] = v.y;
            wreg[i][4 * q + 2] = v.z;
            wreg[i][4 * q + 3] = v.w;
        }
    }

    // ---- streamed rows i=2..7: fixed base addresses for the whole kernel ----
    const float* sp[6];
#pragma unroll
    for (int i = 0; i < 6; ++i)
        sp[i] = Whh + (size_t)((i + 2) * 64 + l) * Hsz + kb;

    h_lds[tid] = 0.f;                // tid < 512 == Hsz
    __syncthreads();

    float* outb = out + (size_t)b * Ssz * Hsz;

    for (int t = 0; t < Ssz; ++t) {
        float* row = outb + (size_t)t * Hsz;
        const float xp = row[tid];          // xproj, issued early (read-before-write)
        const float hv = h_lds[kb + l];     // lane l holds h[kb+l]

        float acc[8];
#pragma unroll
        for (int i = 0; i < 8; ++i) acc[i] = 0.f;

        // ring-3 stream buffer; all indices compile-time after full unroll
        float buf[3][6][4];
#define LOADSUB(S)                                                      \
        {                                                               \
            _Pragma("unroll")                                           \
            for (int i = 0; i < 6; ++i) {                               \
                const float4 v = *(const float4*)(sp[i] + 4 * (S));     \
                buf[(S) % 3][i][0] = v.x;                               \
                buf[(S) % 3][i][1] = v.y;                               \
                buf[(S) % 3][i][2] = v.z;                               \
                buf[(S) % 3][i][3] = v.w;                               \
            }                                                           \
        }

        LOADSUB(0)
        LOADSUB(1)

#pragma unroll
        for (int sub = 0; sub < 16; ++sub) {
            // prefetch sub+2 into slot (sub+2)%3 != sub%3 (no clobber)
            if (sub < 14) LOADSUB(sub + 2)
#pragma unroll
            for (int j = 0; j < 4; ++j) {
                const int kk = sub * 4 + j;
                const float s = bcast_lane(hv, kk);   // SGPR broadcast
                acc[0] = fmaf(wreg[0][kk], s, acc[0]);
                acc[1] = fmaf(wreg[1][kk], s, acc[1]);
#pragma unroll
                for (int i = 0; i < 6; ++i)
                    acc[2 + i] = fmaf(buf[sub % 3][i][j], s, acc[2 + i]);
            }
        }
#undef LOADSUB

        // partials: wave w writes its k-chunk contribution for all its rows
#pragma unroll
        for (int i = 0; i < 8; ++i) pt[w][i * 64 + l] = acc[i];
        __syncthreads();

        // reduce: thread 'tid' owns output row 'tid'
        float ssum = xp;
#pragma unroll
        for (int c = 0; c < 8; ++c) ssum += pt[c][tid];
        const float hn = tanhf(ssum);
        h_lds[tid] = hn;             // publish h_t for next step
        row[tid]   = hn;             // emit output (coalesced 2 KB)
        __syncthreads();
    }
}

// ============================================================================
extern "C" void kernel_launch(void* const* d_in, const int* in_sizes, int n_in,
                              void* d_out, int out_size, void* d_ws, size_t ws_size,
                              hipStream_t stream)
{
    const float* x   = (const float*)d_in[0];   // (B,S,I)
    const float* Wih = (const float*)d_in[1];   // (H,I)
    const float* Whh = (const float*)d_in[2];   // (H,H)
    const float* bih = (const float*)d_in[3];   // (H)
    const float* bhh = (const float*)d_in[4];   // (H)
    float* out = (float*)d_out;                 // (B,S,H)

    dim3 g1(Hsz / 128, (Bsz * Ssz) / 128);      // (4, 1024)
    xproj_gemm<<<g1, 256, 0, stream>>>(x, Wih, bih, bhh, out);

    rnn_scan<<<Bsz, 512, 0, stream>>>(Whh, out);
}